// Round 10
// baseline (756.253 us; speedup 1.0000x reference)
//
#include <hip/hip_runtime.h>
#include <math.h>

#define NN 100000
#define EIN 800000
#define EEX 400000
#define ND 35
#define H 128
#define NG 256
#define NL 4
#define TM 16          // nodes per tile (MFMA M)
#define TML 16         // nodes per block in k_lin_node
#define NTILES 6250    // NN/TM

typedef unsigned short u16;
typedef short s8v __attribute__((ext_vector_type(8)));   // 8 bf16 (4 VGPRs)
typedef float f4v __attribute__((ext_vector_type(4)));   // 4 fp32 acc

__device__ __forceinline__ float silu_f(float x){ return x / (1.0f + expf(-x)); }
__device__ __forceinline__ float bf2f(u16 v){ return __uint_as_float(((unsigned)v) << 16); }
__device__ __forceinline__ u16 f2bf(float f){
  unsigned u = __float_as_uint(f);
  u += 0x7FFFu + ((u >> 16) & 1u);   // RNE
  return (u16)(u >> 16);
}

// ---------------- tile helpers ----------------
__device__ __forceinline__ void tile_gather(const u16* __restrict__ hin, int n0, int tid,
    const int* __restrict__ rowI, const int* __restrict__ cntI,
    const int* __restrict__ colI, const float* __restrict__ valI,
    const int* __restrict__ rowE, const int* __restrict__ cntE,
    const int* __restrict__ colE, const float* __restrict__ valE,
    u16 (*aggIs)[136], u16 (*aggEs)[136])
{
  const int slot = tid >> 4;
  const int l16  = tid & 15;
  const int j8 = l16 * 8;
  const int n = n0 + slot;
  #pragma unroll
  for (int list = 0; list < 2; ++list){
    const int*   rowp = list ? rowE : rowI;
    const int*   cntp = list ? cntE : cntI;
    const int*   colp = list ? colE : colI;
    const float* valp = list ? valE : valI;
    float a[8];
    #pragma unroll
    for (int u = 0; u < 8; ++u) a[u] = 0.f;
    const int s = rowp[n], c = cntp[n];
    int tt = 0;
    for (; tt + 4 <= c; tt += 4){
      int cc[4]; float vv[4];
      #pragma unroll
      for (int u = 0; u < 4; ++u){ cc[u] = colp[s+tt+u]; vv[u] = valp[s+tt+u]; }
      uint4 hh[4];
      #pragma unroll
      for (int u = 0; u < 4; ++u) hh[u] = *(const uint4*)(hin + (size_t)cc[u]*H + j8);
      #pragma unroll
      for (int u = 0; u < 4; ++u){
        a[0] += __uint_as_float(hh[u].x << 16)          * vv[u];
        a[1] += __uint_as_float(hh[u].x & 0xffff0000u)  * vv[u];
        a[2] += __uint_as_float(hh[u].y << 16)          * vv[u];
        a[3] += __uint_as_float(hh[u].y & 0xffff0000u)  * vv[u];
        a[4] += __uint_as_float(hh[u].z << 16)          * vv[u];
        a[5] += __uint_as_float(hh[u].z & 0xffff0000u)  * vv[u];
        a[6] += __uint_as_float(hh[u].w << 16)          * vv[u];
        a[7] += __uint_as_float(hh[u].w & 0xffff0000u)  * vv[u];
      }
    }
    for (; tt < c; ++tt){
      const int c0 = colp[s+tt];
      const float v0 = valp[s+tt];
      const uint4 h0 = *(const uint4*)(hin + (size_t)c0*H + j8);
      a[0] += __uint_as_float(h0.x << 16)         * v0;
      a[1] += __uint_as_float(h0.x & 0xffff0000u) * v0;
      a[2] += __uint_as_float(h0.y << 16)         * v0;
      a[3] += __uint_as_float(h0.y & 0xffff0000u) * v0;
      a[4] += __uint_as_float(h0.z << 16)         * v0;
      a[5] += __uint_as_float(h0.z & 0xffff0000u) * v0;
      a[6] += __uint_as_float(h0.w << 16)         * v0;
      a[7] += __uint_as_float(h0.w & 0xffff0000u) * v0;
    }
    const unsigned p0 = (unsigned)f2bf(a[0]) | ((unsigned)f2bf(a[1]) << 16);
    const unsigned p1 = (unsigned)f2bf(a[2]) | ((unsigned)f2bf(a[3]) << 16);
    const unsigned p2 = (unsigned)f2bf(a[4]) | ((unsigned)f2bf(a[5]) << 16);
    const unsigned p3 = (unsigned)f2bf(a[6]) | ((unsigned)f2bf(a[7]) << 16);
    u16* drow = list ? &aggEs[slot][j8] : &aggIs[slot][j8];
    *(uint4*)drow = make_uint4(p0, p1, p2, p3);
  }
}

__device__ __forceinline__ void tile_mfma(const u16 (*aggIs)[136], const u16 (*aggEs)[136],
    const u16* __restrict__ WfIl, const u16* __restrict__ WfEl,
    int lane, int jta, int jtb,
    f4v& accIA, f4v& accIB, f4v& accEA, f4v& accEB)
{
  const int col  = lane & 15;
  const int quad = lane >> 4;
  accIA = (f4v){0.f,0.f,0.f,0.f}; accIB = (f4v){0.f,0.f,0.f,0.f};
  accEA = (f4v){0.f,0.f,0.f,0.f}; accEB = (f4v){0.f,0.f,0.f,0.f};
  #pragma unroll
  for (int kc = 0; kc < 4; ++kc){
    const int koff = kc*32 + quad*8;
    const s8v aI = *(const s8v*)&aggIs[col][koff];
    const s8v aE = *(const s8v*)&aggEs[col][koff];
    const s8v bIA = *(const s8v*)(WfIl + (((jta*4 + kc)*64 + lane) << 3));
    const s8v bIB = *(const s8v*)(WfIl + (((jtb*4 + kc)*64 + lane) << 3));
    const s8v bEA = *(const s8v*)(WfEl + (((jta*4 + kc)*64 + lane) << 3));
    const s8v bEB = *(const s8v*)(WfEl + (((jtb*4 + kc)*64 + lane) << 3));
    accIA = __builtin_amdgcn_mfma_f32_16x16x32_bf16(aI, bIA, accIA, 0, 0, 0);
    accIB = __builtin_amdgcn_mfma_f32_16x16x32_bf16(aI, bIB, accIB, 0, 0, 0);
    accEA = __builtin_amdgcn_mfma_f32_16x16x32_bf16(aE, bEA, accEA, 0, 0, 0);
    accEB = __builtin_amdgcn_mfma_f32_16x16x32_bf16(aE, bEB, accEB, 0, 0, 0);
  }
}

// ---------------- lin_node: h = silu(x @ W + b) -> bf16 ----------------
__global__ __launch_bounds__(256) void k_lin_node(const float* __restrict__ x,
                                                  const float* __restrict__ W,
                                                  const float* __restrict__ b,
                                                  u16* __restrict__ h){
  __shared__ float Ws[ND*H];
  __shared__ float xs[TML*ND];
  const int n0 = blockIdx.x * TML;
  for (int i = threadIdx.x; i < ND*H; i += 256) Ws[i] = W[i];
  for (int i = threadIdx.x; i < TML*ND; i += 256) xs[i] = x[(size_t)n0*ND + i];
  __syncthreads();
  const int j = threadIdx.x & (H-1);
  const int half = threadIdx.x >> 7;
  const float bj = b[j];
  #pragma unroll
  for (int r = 0; r < TML/2; ++r){
    const int m = half + 2*r;
    float acc = bj;
    #pragma unroll
    for (int k = 0; k < ND; ++k) acc += xs[m*ND + k] * Ws[k*H + j];
    h[(size_t)(n0+m)*H + j] = f2bf(silu_f(acc));
  }
}

// ---------------- weight -> bf16 B-fragment swizzle ----------------
__global__ void k_wfrag(const float* __restrict__ WI, const float* __restrict__ WE,
                        u16* __restrict__ WfI, u16* __restrict__ WfE){
  const int lm = blockIdx.x;            // 0..2*NL-1
  const int l = lm >> 1;
  const float* src = (lm & 1) ? (WE + (size_t)l*H*H) : (WI + (size_t)l*H*H);
  u16* dst = ((lm & 1) ? WfE : WfI) + (size_t)l*H*H;
  for (int idx = threadIdx.x; idx < H*H; idx += 256){
    const int r = idx & 7, lane = (idx>>3)&63, kc = (idx>>9)&3, jt = idx>>11;
    const int k = kc*32 + (lane>>4)*8 + r;
    const int j = jt*16 + (lane&15);
    dst[idx] = f2bf(src[k*H + j]);
  }
}

// ---------------- combined degree count (intra+inter) ----------------
__global__ void k_count_all(const int* __restrict__ dst_i, const int* __restrict__ dst_e,
                            int* __restrict__ cnt_i, int* __restrict__ cnt_e){
  int e = blockIdx.x*256 + threadIdx.x;
  if (e < EIN) atomicAdd(&cnt_i[dst_i[e]], 1);
  else if (e < EIN + EEX) atomicAdd(&cnt_e[dst_e[e - EIN]], 1);
}

// ---------------- combined 2-level scan ----------------
__global__ void k_block_sum_all(const int* __restrict__ cnt_i, const int* __restrict__ cnt_e,
                                int* __restrict__ bsum){
  __shared__ int s[256];
  const int NB = (NN + 255)/256;
  const bool inter = (int)blockIdx.x >= NB;
  const int* cnt = inter ? cnt_e : cnt_i;
  int* bs = bsum + (inter ? 512 : 0);
  const int b = inter ? blockIdx.x - NB : blockIdx.x;
  int i = b*256 + threadIdx.x;
  s[threadIdx.x] = (i < NN) ? cnt[i] : 0;
  __syncthreads();
  for (int o = 128; o > 0; o >>= 1){
    if (threadIdx.x < o) s[threadIdx.x] += s[threadIdx.x + o];
    __syncthreads();
  }
  if (threadIdx.x == 0) bs[b] = s[0];
}
__global__ void k_scan_top_all(int* __restrict__ bsum){
  __shared__ int s[512];
  int* bs = bsum + (blockIdx.x ? 512 : 0);
  const int NB = (NN + 255)/256;
  int t = threadIdx.x;
  int v = (t < NB) ? bs[t] : 0;
  s[t] = v; __syncthreads();
  for (int o = 1; o < 512; o <<= 1){
    int a = (t >= o) ? s[t-o] : 0;
    __syncthreads();
    s[t] += a;
    __syncthreads();
  }
  if (t < NB) bs[t] = s[t] - v;   // exclusive
}
__global__ void k_scan_write_all(const int* __restrict__ cnt_i, const int* __restrict__ cnt_e,
                                 const int* __restrict__ bsum,
                                 int* __restrict__ row_i, int* __restrict__ cur_i,
                                 int* __restrict__ row_e, int* __restrict__ cur_e){
  __shared__ int s[256];
  const int NB = (NN + 255)/256;
  const bool inter = (int)blockIdx.x >= NB;
  const int* cnt = inter ? cnt_e : cnt_i;
  const int* bs = bsum + (inter ? 512 : 0);
  int* rowp = inter ? row_e : row_i;
  int* curp = inter ? cur_e : cur_i;
  const int b = inter ? blockIdx.x - NB : blockIdx.x;
  int t = threadIdx.x, i = b*256 + t;
  int v = (i < NN) ? cnt[i] : 0;
  s[t] = v; __syncthreads();
  for (int o = 1; o < 256; o <<= 1){
    int a = (t >= o) ? s[t-o] : 0;
    __syncthreads();
    s[t] += a;
    __syncthreads();
  }
  if (i < NN){
    int ex = bs[b] + s[t] - v;
    rowp[i] = ex; curp[i] = ex;
  }
}

// ---------------- combined CSR fill ----------------
__global__ void k_fill_all(const int* __restrict__ src_i, const int* __restrict__ dst_i,
                           const float* __restrict__ ea,
                           const int* __restrict__ src_e, const int* __restrict__ dst_e,
                           const float* __restrict__ pos,
                           int* __restrict__ cur_i, int* __restrict__ col_i, float* __restrict__ val_i,
                           int* __restrict__ cur_e, int* __restrict__ col_e, float* __restrict__ val_e){
  int e = blockIdx.x*256 + threadIdx.x;
  if (e < EIN){
    int d = dst_i[e];
    int slot = atomicAdd(&cur_i[d], 1);
    col_i[slot] = src_i[e];
    val_i[slot] = ea[e];
  } else if (e < EIN + EEX){
    int ee = e - EIN;
    int s = src_e[ee], d = dst_e[ee];
    float dx = pos[3*s+0] - pos[3*d+0];
    float dy = pos[3*s+1] - pos[3*d+1];
    float dz = pos[3*s+2] - pos[3*d+2];
    float w = expf(-(dx*dx + dy*dy + dz*dz));
    int slot = atomicAdd(&cur_e[d], 1);
    col_e[slot] = s;
    val_e[slot] = w;
  }
}

// ---------------- specialized layer: MODE 0=first, 1=mid, 2=last ----------------
// All loads/stores unconditional per variant; epilogue operands loaded EARLY
// (before gather) so their latency hides under the gather phase.
template<int MODE>
__global__ __launch_bounds__(256) void k_layer_t(
    const u16* __restrict__ hin, u16* __restrict__ hout,
    u16* __restrict__ vp, u16* __restrict__ vl,
    const int* __restrict__ rowI, const int* __restrict__ cntI,
    const int* __restrict__ colI, const float* __restrict__ valI,
    const int* __restrict__ rowE, const int* __restrict__ cntE,
    const int* __restrict__ colE, const float* __restrict__ valE,
    const u16* __restrict__ WfIl, const float* __restrict__ bIl,
    const u16* __restrict__ WfEl, const float* __restrict__ bEl,
    const int* __restrict__ batch, float* __restrict__ gp)
{
  __shared__ __align__(16) u16 aggIs[TM][136];
  __shared__ __align__(16) u16 aggEs[TM][136];
  const int tid = threadIdx.x;
  const int n0 = blockIdx.x * TM;
  const int lane = tid & 63;
  const int wv   = tid >> 6;
  const int quad = lane >> 4;
  const int jta = 2*wv, jtb = 2*wv + 1;
  const int col  = lane & 15;
  const int j0g = jta*16 + col;
  const int j1g = jtb*16 + col;

  // ---- early epilogue-operand loads (overlap with gather below) ----
  u16 ehin0[4], ehin1[4];
  u16 evp0[4], evp1[4], evl0[4], evl1[4];
  int ecI[4], ecE[4];
  int ebatch[4];
  #pragma unroll
  for (int r = 0; r < 4; ++r){
    const int n = n0 + quad*4 + r;
    const size_t i0 = (size_t)n*H + j0g;
    const size_t i1 = (size_t)n*H + j1g;
    ehin0[r] = hin[i0]; ehin1[r] = hin[i1];
    ecI[r] = cntI[n];   ecE[r] = cntE[n];
    if (MODE != 0){ evp0[r] = vp[i0]; evp1[r] = vp[i1]; evl0[r] = vl[i0]; evl1[r] = vl[i1]; }
    if (MODE == 2) ebatch[r] = batch[n];
  }
  int bU0 = 0, bU1 = 0;
  if (MODE == 2){ bU0 = batch[n0]; bU1 = batch[n0 + TM - 1]; }

  tile_gather(hin, n0, tid, rowI, cntI, colI, valI, rowE, cntE, colE, valE, aggIs, aggEs);
  __syncthreads();
  f4v accIA, accIB, accEA, accEB;
  tile_mfma(aggIs, aggEs, WfIl, WfEl, lane, jta, jtb, accIA, accIB, accEA, accEB);

  float hf0[4], hf1[4];
  #pragma unroll
  for (int r = 0; r < 4; ++r){
    const int n = n0 + quad*4 + r;
    const float cI = (float)ecI[r];
    const float cE = (float)ecE[r];
    const float rdI = 1.0f / (cI + 1.0f);
    const float ldE = logf(cE + 1.0f);
    const float vp0 = (MODE == 0) ? 0.f : bf2f(evp0[r]);
    const float vp1 = (MODE == 0) ? 0.f : bf2f(evp1[r]);
    const float vl0 = (MODE == 0) ? 0.f : bf2f(evl0[r]);
    const float vl1 = (MODE == 0) ? 0.f : bf2f(evl1[r]);
    const float mi0 = (accIA[r] + cI*bIl[j0g]) * rdI;
    const float me0 = (accEA[r] + cE*bEl[j0g]) * ldE;
    const float mi1 = (accIB[r] + cI*bIl[j1g]) * rdI;
    const float me1 = (accEB[r] + cE*bEl[j1g]) * ldE;
    const float vpn0 = silu_f(mi0 + vp0);
    const float vln0 = silu_f(me0 + vl0);
    const float vpn1 = silu_f(mi1 + vp1);
    const float vln1 = silu_f(me1 + vl1);
    const float h0 = bf2f(ehin0[r]) + vpn0 + vln0;
    const float h1 = bf2f(ehin1[r]) + vpn1 + vln1;
    if (MODE != 2){
      const size_t i0 = (size_t)n*H + j0g;
      const size_t i1 = (size_t)n*H + j1g;
      vp[i0] = f2bf(vpn0); vp[i1] = f2bf(vpn1);
      vl[i0] = f2bf(vln0); vl[i1] = f2bf(vln1);
      hout[i0] = f2bf(h0);
      hout[i1] = f2bf(h1);
    } else {
      hf0[r] = h0; hf1[r] = h1;
    }
  }

  if (MODE == 2){
    if (bU0 == bU1){
      // tile entirely in one graph (~96% of tiles): wave-reduce across quads -> 1 atomic/j
      float s0 = hf0[0] + hf0[1] + hf0[2] + hf0[3];
      float s1 = hf1[0] + hf1[1] + hf1[2] + hf1[3];
      s0 += __shfl_xor(s0, 16, 64); s0 += __shfl_xor(s0, 32, 64);
      s1 += __shfl_xor(s1, 16, 64); s1 += __shfl_xor(s1, 32, 64);
      if (quad == 0){
        atomicAdd(&gp[(size_t)bU0*H + j0g], s0);
        atomicAdd(&gp[(size_t)bU0*H + j1g], s1);
      }
    } else {
      int bprev = ebatch[0];
      float a0 = 0.f, a1 = 0.f;
      #pragma unroll
      for (int r = 0; r < 4; ++r){
        const int bcur = ebatch[r];
        if (bcur != bprev){
          atomicAdd(&gp[(size_t)bprev*H + j0g], a0);
          atomicAdd(&gp[(size_t)bprev*H + j1g], a1);
          a0 = 0.f; a1 = 0.f; bprev = bcur;
        }
        a0 += hf0[r]; a1 += hf1[r];
      }
      atomicAdd(&gp[(size_t)bprev*H + j0g], a0);
      atomicAdd(&gp[(size_t)bprev*H + j1g], a1);
    }
  }
}

// ---------------- FC head ----------------
__global__ void k_fc(const float* __restrict__ g, const float* __restrict__ fcW,
                     const float* __restrict__ fcb, const float* __restrict__ gamma,
                     const float* __restrict__ beta, const float* __restrict__ outW,
                     const float* __restrict__ outb, float* __restrict__ out){
  __shared__ float row[H];
  __shared__ float red[H];
  const int gi = blockIdx.x;
  const int j = threadIdx.x;
  row[j] = g[(size_t)gi*H + j];
  __syncthreads();
  const float bn_scale = rsqrtf(1.0f + 1e-5f);
  for (int l = 0; l < 3; ++l){
    const float* W = fcW + (size_t)l*H*H;
    float acc = fcb[l*H + j];
    #pragma unroll 8
    for (int k = 0; k < H; ++k) acc += row[k] * W[k*H + j];
    acc = (acc > 0.f) ? acc : 0.01f*acc;
    acc = acc * bn_scale * gamma[l*H + j] + beta[l*H + j];
    __syncthreads();
    row[j] = acc;
    __syncthreads();
  }
  red[j] = row[j] * outW[j];
  __syncthreads();
  for (int o = 64; o > 0; o >>= 1){
    if (j < o) red[j] += red[j + o];
    __syncthreads();
  }
  if (j == 0) out[gi] = red[0] + outb[0];
}

extern "C" void kernel_launch(void* const* d_in, const int* in_sizes, int n_in,
                              void* d_out, int out_size, void* d_ws, size_t ws_size,
                              hipStream_t stream)
{
  const float* x    = (const float*)d_in[0];
  const int*   eii  = (const int*)  d_in[1];
  const int*   eie  = (const int*)  d_in[2];
  const float* pos  = (const float*)d_in[3];
  const float* ea   = (const float*)d_in[4];
  const int*   batch= (const int*)  d_in[5];
  const float* lnW  = (const float*)d_in[6];
  const float* lnb  = (const float*)d_in[7];
  const float* WIa  = (const float*)d_in[8];
  const float* bIa  = (const float*)d_in[9];
  const float* WEa  = (const float*)d_in[10];
  const float* bEa  = (const float*)d_in[11];
  const float* fcW  = (const float*)d_in[12];
  const float* fcb  = (const float*)d_in[13];
  const float* gam  = (const float*)d_in[14];
  const float* bet  = (const float*)d_in[15];
  const float* outW = (const float*)d_in[16];
  const float* outb = (const float*)d_in[17];
  float* out = (float*)d_out;

  const int* src_i = eii;  const int* dst_i = eii + EIN;
  const int* src_e = eie;  const int* dst_e = eie + EEX;

  const size_t NH = (size_t)NN * H;
  u16* hA = (u16*)d_ws;                    // NH bf16
  u16* hB = hA + NH;
  u16* vp = hB + NH;                       // NH bf16
  u16* vl = vp + NH;
  float* gp = (float*)(vl + NH);           // NG*H
  int* cnt_i = (int*)(gp + (size_t)NG*H);  // NN
  int* cnt_e = cnt_i + NN;
  int* row_i = cnt_e + NN;
  int* row_e = row_i + NN;
  int* cur_i = row_e + NN;
  int* cur_e = cur_i + NN;
  int* col_i = cur_e + NN;                 // EIN
  float* val_i = (float*)(col_i + EIN);    // EIN
  int* col_e = (int*)(val_i + EIN);        // EEX
  float* val_e = (float*)(col_e + EEX);    // EEX
  int* bsum = (int*)(val_e + EEX);         // 1024
  u16* WfI = (u16*)(bsum + 1024);          // NL*H*H bf16
  u16* WfE = WfI + (size_t)NL*H*H;

  const size_t need = 4*NH*sizeof(u16)
                    + ((size_t)NG*H + 6*(size_t)NN + 2*(size_t)EIN + 2*(size_t)EEX + 1024)*4
                    + 2*(size_t)NL*H*H*sizeof(u16);
  if (ws_size < need) return;

  // zero gp + cnt_i + cnt_e (contiguous); vp/vl need no init (layer 0 writes before read)
  hipMemsetAsync(gp, 0, (size_t)NG*H*sizeof(float) + 2*(size_t)NN*sizeof(int), stream);

  k_wfrag<<<2*NL, 256, 0, stream>>>(WIa, WEa, WfI, WfE);
  k_lin_node<<<NN/TML, 256, 0, stream>>>(x, lnW, lnb, hA);

  const int NE_ALL = EIN + EEX;
  k_count_all<<<(NE_ALL+255)/256, 256, 0, stream>>>(dst_i, dst_e, cnt_i, cnt_e);

  const int NB = (NN + 255)/256;  // 391
  k_block_sum_all<<<2*NB, 256, 0, stream>>>(cnt_i, cnt_e, bsum);
  k_scan_top_all<<<2, 512, 0, stream>>>(bsum);
  k_scan_write_all<<<2*NB, 256, 0, stream>>>(cnt_i, cnt_e, bsum, row_i, cur_i, row_e, cur_e);
  k_fill_all<<<(NE_ALL+255)/256, 256, 0, stream>>>(src_i, dst_i, ea, src_e, dst_e, pos,
                                                   cur_i, col_i, val_i, cur_e, col_e, val_e);

  // layer 0: hA -> hB ; layer 1: hB -> hA ; layer 2: hA -> hB ; layer 3: reads hB
  k_layer_t<0><<<NTILES, 256, 0, stream>>>(hA, hB, vp, vl,
      row_i, cnt_i, col_i, val_i, row_e, cnt_e, col_e, val_e,
      WfI + 0*(size_t)H*H, bIa + 0*H, WfE + 0*(size_t)H*H, bEa + 0*H, batch, gp);
  k_layer_t<1><<<NTILES, 256, 0, stream>>>(hB, hA, vp, vl,
      row_i, cnt_i, col_i, val_i, row_e, cnt_e, col_e, val_e,
      WfI + 1*(size_t)H*H, bIa + 1*H, WfE + 1*(size_t)H*H, bEa + 1*H, batch, gp);
  k_layer_t<1><<<NTILES, 256, 0, stream>>>(hA, hB, vp, vl,
      row_i, cnt_i, col_i, val_i, row_e, cnt_e, col_e, val_e,
      WfI + 2*(size_t)H*H, bIa + 2*H, WfE + 2*(size_t)H*H, bEa + 2*H, batch, gp);
  k_layer_t<2><<<NTILES, 256, 0, stream>>>(hB, hA, vp, vl,
      row_i, cnt_i, col_i, val_i, row_e, cnt_e, col_e, val_e,
      WfI + 3*(size_t)H*H, bIa + 3*H, WfE + 3*(size_t)H*H, bEa + 3*H, batch, gp);

  k_fc<<<NG, H, 0, stream>>>(gp, fcW, fcb, gam, bet, outW, outb, out);
}

// Round 11
// 680.623 us; speedup vs baseline: 1.1111x; 1.1111x over previous
//
#include <hip/hip_runtime.h>
#include <math.h>

#define NN 100000
#define EIN 800000
#define EEX 400000
#define ND 35
#define H 128
#define NG 256
#define NL 4
#define TM 16          // nodes per tile (MFMA M)
#define TML 16         // nodes per block in lin_node
#define NTILES 6250    // NN/TM

typedef unsigned short u16;
typedef short s8v __attribute__((ext_vector_type(8)));   // 8 bf16 (4 VGPRs)
typedef float f4v __attribute__((ext_vector_type(4)));   // 4 fp32 acc

__device__ __forceinline__ float silu_f(float x){ return x / (1.0f + expf(-x)); }
__device__ __forceinline__ float bf2f(u16 v){ return __uint_as_float(((unsigned)v) << 16); }
__device__ __forceinline__ u16 f2bf(float f){
  unsigned u = __float_as_uint(f);
  u += 0x7FFFu + ((u >> 16) & 1u);   // RNE
  return (u16)(u >> 16);
}

// ---------------- merged: wfrag (blocks 0..7) + lin_node (blocks 8..) ----------------
// Weight swizzle: Wfrag[((jt*4+kc)*64+lane)*8+r] = bf16(W[kc*32+(lane>>4)*8+r][jt*16+(lane&15)])
__global__ __launch_bounds__(256) void k_prep(const float* __restrict__ x,
                                              const float* __restrict__ lnW,
                                              const float* __restrict__ lnb,
                                              u16* __restrict__ h,
                                              const float* __restrict__ WI,
                                              const float* __restrict__ WE,
                                              u16* __restrict__ WfI,
                                              u16* __restrict__ WfE){
  if (blockIdx.x < 2*NL){
    const int lm = blockIdx.x;
    const int l = lm >> 1;
    const float* src = (lm & 1) ? (WE + (size_t)l*H*H) : (WI + (size_t)l*H*H);
    u16* dst = ((lm & 1) ? WfE : WfI) + (size_t)l*H*H;
    for (int idx = threadIdx.x; idx < H*H; idx += 256){
      const int r = idx & 7, lane = (idx>>3)&63, kc = (idx>>9)&3, jt = idx>>11;
      const int k = kc*32 + (lane>>4)*8 + r;
      const int j = jt*16 + (lane&15);
      dst[idx] = f2bf(src[k*H + j]);
    }
    return;
  }
  __shared__ float Ws[ND*H];
  __shared__ float xs[TML*ND];
  const int n0 = (blockIdx.x - 2*NL) * TML;
  for (int i = threadIdx.x; i < ND*H; i += 256) Ws[i] = lnW[i];
  for (int i = threadIdx.x; i < TML*ND; i += 256) xs[i] = x[(size_t)n0*ND + i];
  __syncthreads();
  const int j = threadIdx.x & (H-1);
  const int half = threadIdx.x >> 7;
  const float bj = lnb[j];
  #pragma unroll
  for (int r = 0; r < TML/2; ++r){
    const int m = half + 2*r;
    float acc = bj;
    #pragma unroll
    for (int k = 0; k < ND; ++k) acc += xs[m*ND + k] * Ws[k*H + j];
    h[(size_t)(n0+m)*H + j] = f2bf(silu_f(acc));
  }
}

// ---------------- combined degree count (intra+inter) ----------------
__global__ void k_count_all(const int* __restrict__ dst_i, const int* __restrict__ dst_e,
                            int* __restrict__ cnt_i, int* __restrict__ cnt_e){
  int e = blockIdx.x*256 + threadIdx.x;
  if (e < EIN) atomicAdd(&cnt_i[dst_i[e]], 1);
  else if (e < EIN + EEX) atomicAdd(&cnt_e[dst_e[e - EIN]], 1);
}

// ---------------- combined 2-level scan ----------------
__global__ void k_block_sum_all(const int* __restrict__ cnt_i, const int* __restrict__ cnt_e,
                                int* __restrict__ bsum){
  __shared__ int s[256];
  const int NB = (NN + 255)/256;
  const bool inter = (int)blockIdx.x >= NB;
  const int* cnt = inter ? cnt_e : cnt_i;
  int* bs = bsum + (inter ? 512 : 0);
  const int b = inter ? blockIdx.x - NB : blockIdx.x;
  int i = b*256 + threadIdx.x;
  s[threadIdx.x] = (i < NN) ? cnt[i] : 0;
  __syncthreads();
  for (int o = 128; o > 0; o >>= 1){
    if (threadIdx.x < o) s[threadIdx.x] += s[threadIdx.x + o];
    __syncthreads();
  }
  if (threadIdx.x == 0) bs[b] = s[0];
}
__global__ void k_scan_top_all(int* __restrict__ bsum){
  __shared__ int s[512];
  int* bs = bsum + (blockIdx.x ? 512 : 0);
  const int NB = (NN + 255)/256;
  int t = threadIdx.x;
  int v = (t < NB) ? bs[t] : 0;
  s[t] = v; __syncthreads();
  for (int o = 1; o < 512; o <<= 1){
    int a = (t >= o) ? s[t-o] : 0;
    __syncthreads();
    s[t] += a;
    __syncthreads();
  }
  if (t < NB) bs[t] = s[t] - v;   // exclusive
}
__global__ void k_scan_write_all(const int* __restrict__ cnt_i, const int* __restrict__ cnt_e,
                                 const int* __restrict__ bsum,
                                 int* __restrict__ row_i, int* __restrict__ cur_i,
                                 int* __restrict__ row_e, int* __restrict__ cur_e){
  __shared__ int s[256];
  const int NB = (NN + 255)/256;
  const bool inter = (int)blockIdx.x >= NB;
  const int* cnt = inter ? cnt_e : cnt_i;
  const int* bs = bsum + (inter ? 512 : 0);
  int* rowp = inter ? row_e : row_i;
  int* curp = inter ? cur_e : cur_i;
  const int b = inter ? blockIdx.x - NB : blockIdx.x;
  int t = threadIdx.x, i = b*256 + t;
  int v = (i < NN) ? cnt[i] : 0;
  s[t] = v; __syncthreads();
  for (int o = 1; o < 256; o <<= 1){
    int a = (t >= o) ? s[t-o] : 0;
    __syncthreads();
    s[t] += a;
    __syncthreads();
  }
  if (i < NN){
    int ex = bs[b] + s[t] - v;
    rowp[i] = ex; curp[i] = ex;
  }
}

// ---------------- combined CSR fill ----------------
__global__ void k_fill_all(const int* __restrict__ src_i, const int* __restrict__ dst_i,
                           const float* __restrict__ ea,
                           const int* __restrict__ src_e, const int* __restrict__ dst_e,
                           const float* __restrict__ pos,
                           int* __restrict__ cur_i, int* __restrict__ col_i, float* __restrict__ val_i,
                           int* __restrict__ cur_e, int* __restrict__ col_e, float* __restrict__ val_e){
  int e = blockIdx.x*256 + threadIdx.x;
  if (e < EIN){
    int d = dst_i[e];
    int slot = atomicAdd(&cur_i[d], 1);
    col_i[slot] = src_i[e];
    val_i[slot] = ea[e];
  } else if (e < EIN + EEX){
    int ee = e - EIN;
    int s = src_e[ee], d = dst_e[ee];
    float dx = pos[3*s+0] - pos[3*d+0];
    float dy = pos[3*s+1] - pos[3*d+1];
    float dz = pos[3*s+2] - pos[3*d+2];
    float w = expf(-(dx*dx + dy*dy + dz*dz));
    int slot = atomicAdd(&cur_e[d], 1);
    col_e[slot] = s;
    val_e[slot] = w;
  }
}

// ---------------- fused layer (R6-verbatim): gather(bf16) -> MFMA -> epilogue ----------------
__global__ __launch_bounds__(256) void k_layer(
    const u16* __restrict__ hin, u16* __restrict__ hout,
    u16* __restrict__ vp, u16* __restrict__ vl,
    const int* __restrict__ rowI, const int* __restrict__ cntI,
    const int* __restrict__ colI, const float* __restrict__ valI,
    const int* __restrict__ rowE, const int* __restrict__ cntE,
    const int* __restrict__ colE, const float* __restrict__ valE,
    const u16* __restrict__ WfI, const float* __restrict__ bI,   // B-fragment order, bf16
    const u16* __restrict__ WfE, const float* __restrict__ bE)
{
  // A-operand layout (m120-verified): A[m=lane&15][k=quad*8+j]; rows padded to 136
  __shared__ u16 aggIs[TM][136];
  __shared__ u16 aggEs[TM][136];
  const int n0 = blockIdx.x * TM;
  const int tid = threadIdx.x;

  // ---- gather phase: thread = (slot 0..15 -> node, l16 0..15 -> 8 bf16 chans) ----
  {
    const int slot = tid >> 4;
    const int l16  = tid & 15;
    const int j8 = l16 * 8;
    const int n = n0 + slot;

    #pragma unroll
    for (int list = 0; list < 2; ++list){
      const int*   rowp = list ? rowE : rowI;
      const int*   cntp = list ? cntE : cntI;
      const int*   colp = list ? colE : colI;
      const float* valp = list ? valE : valI;
      float a[8];
      #pragma unroll
      for (int u = 0; u < 8; ++u) a[u] = 0.f;
      const int s = rowp[n], c = cntp[n];
      int t = 0;
      for (; t + 4 <= c; t += 4){
        int cc[4]; float vv[4];
        #pragma unroll
        for (int u = 0; u < 4; ++u){ cc[u] = colp[s+t+u]; vv[u] = valp[s+t+u]; }
        uint4 hh[4];
        #pragma unroll
        for (int u = 0; u < 4; ++u) hh[u] = *(const uint4*)(hin + (size_t)cc[u]*H + j8);
        #pragma unroll
        for (int u = 0; u < 4; ++u){
          a[0] += __uint_as_float(hh[u].x << 16)          * vv[u];
          a[1] += __uint_as_float(hh[u].x & 0xffff0000u)  * vv[u];
          a[2] += __uint_as_float(hh[u].y << 16)          * vv[u];
          a[3] += __uint_as_float(hh[u].y & 0xffff0000u)  * vv[u];
          a[4] += __uint_as_float(hh[u].z << 16)          * vv[u];
          a[5] += __uint_as_float(hh[u].z & 0xffff0000u)  * vv[u];
          a[6] += __uint_as_float(hh[u].w << 16)          * vv[u];
          a[7] += __uint_as_float(hh[u].w & 0xffff0000u)  * vv[u];
        }
      }
      for (; t < c; ++t){
        const int c0 = colp[s+t];
        const float v0 = valp[s+t];
        const uint4 h0 = *(const uint4*)(hin + (size_t)c0*H + j8);
        a[0] += __uint_as_float(h0.x << 16)         * v0;
        a[1] += __uint_as_float(h0.x & 0xffff0000u) * v0;
        a[2] += __uint_as_float(h0.y << 16)         * v0;
        a[3] += __uint_as_float(h0.y & 0xffff0000u) * v0;
        a[4] += __uint_as_float(h0.z << 16)         * v0;
        a[5] += __uint_as_float(h0.z & 0xffff0000u) * v0;
        a[6] += __uint_as_float(h0.w << 16)         * v0;
        a[7] += __uint_as_float(h0.w & 0xffff0000u) * v0;
      }
      const unsigned p0 = (unsigned)f2bf(a[0]) | ((unsigned)f2bf(a[1]) << 16);
      const unsigned p1 = (unsigned)f2bf(a[2]) | ((unsigned)f2bf(a[3]) << 16);
      const unsigned p2 = (unsigned)f2bf(a[4]) | ((unsigned)f2bf(a[5]) << 16);
      const unsigned p3 = (unsigned)f2bf(a[6]) | ((unsigned)f2bf(a[7]) << 16);
      u16* drow = list ? &aggEs[slot][j8] : &aggIs[slot][j8];
      *(uint4*)drow = make_uint4(p0, p1, p2, p3);
    }
  }
  __syncthreads();

  // ---- MFMA phase: wave w owns j-tiles {2w, 2w+1} for BOTH mats ----
  const int lane = tid & 63;
  const int w    = tid >> 6;
  const int jta = 2*w, jtb = 2*w + 1;
  const int col  = lane & 15;
  const int quad = lane >> 4;

  f4v accIA = {0.f,0.f,0.f,0.f}, accIB = {0.f,0.f,0.f,0.f};
  f4v accEA = {0.f,0.f,0.f,0.f}, accEB = {0.f,0.f,0.f,0.f};

  #pragma unroll
  for (int kc = 0; kc < 4; ++kc){
    const int koff = kc*32 + quad*8;
    const s8v aI = *(const s8v*)&aggIs[col][koff];
    const s8v aE = *(const s8v*)&aggEs[col][koff];
    const s8v bIA = *(const s8v*)(WfI + (((jta*4 + kc)*64 + lane) << 3));
    const s8v bIB = *(const s8v*)(WfI + (((jtb*4 + kc)*64 + lane) << 3));
    const s8v bEA = *(const s8v*)(WfE + (((jta*4 + kc)*64 + lane) << 3));
    const s8v bEB = *(const s8v*)(WfE + (((jtb*4 + kc)*64 + lane) << 3));
    accIA = __builtin_amdgcn_mfma_f32_16x16x32_bf16(aI, bIA, accIA, 0, 0, 0);
    accIB = __builtin_amdgcn_mfma_f32_16x16x32_bf16(aI, bIB, accIB, 0, 0, 0);
    accEA = __builtin_amdgcn_mfma_f32_16x16x32_bf16(aE, bEA, accEA, 0, 0, 0);
    accEB = __builtin_amdgcn_mfma_f32_16x16x32_bf16(aE, bEB, accEB, 0, 0, 0);
  }

  // ---- epilogue: C/D layout col=lane&15, row=quad*4+reg (m89-verified) ----
  #pragma unroll
  for (int r = 0; r < 4; ++r){
    const int m = quad*4 + r;
    const int n = n0 + m;
    const float cI = (float)cntI[n];
    const float cE = (float)cntE[n];
    const float rdI = 1.0f / (cI + 1.0f);
    const float ldE = logf(cE + 1.0f);
    #pragma unroll
    for (int half = 0; half < 2; ++half){
      const int j = (half ? jtb : jta)*16 + col;
      const float aIv = half ? accIB[r] : accIA[r];
      const float aEv = half ? accEB[r] : accEA[r];
      const float mi = (aIv + cI*bI[j]) * rdI;
      const float me = (aEv + cE*bE[j]) * ldE;
      const size_t idx = (size_t)n*H + j;
      const float vpn = silu_f(mi + bf2f(vp[idx]));
      const float vln = silu_f(me + bf2f(vl[idx]));
      vp[idx] = f2bf(vpn); vl[idx] = f2bf(vln);
      hout[idx] = f2bf(bf2f(hin[idx]) + vpn + vln);
    }
  }
}

// ---------------- pool: batch sorted; register-accumulate, flush on boundary ----------------
__global__ void k_pool(const u16* __restrict__ h, const int* __restrict__ batch,
                       float* __restrict__ g){
  const int j = threadIdx.x;
  const int n0 = blockIdx.x * 64;
  int nend = n0 + 64; if (nend > NN) nend = NN;
  float acc = 0.f;
  int cur = batch[n0];
  for (int n = n0; n < nend; ++n){
    int b = batch[n];
    if (b != cur){
      atomicAdd(&g[(size_t)cur*H + j], acc);
      acc = 0.f; cur = b;
    }
    acc += bf2f(h[(size_t)n*H + j]);
  }
  atomicAdd(&g[(size_t)cur*H + j], acc);
}

// ---------------- FC head ----------------
__global__ void k_fc(const float* __restrict__ g, const float* __restrict__ fcW,
                     const float* __restrict__ fcb, const float* __restrict__ gamma,
                     const float* __restrict__ beta, const float* __restrict__ outW,
                     const float* __restrict__ outb, float* __restrict__ out){
  __shared__ float row[H];
  __shared__ float red[H];
  const int gi = blockIdx.x;
  const int j = threadIdx.x;
  row[j] = g[(size_t)gi*H + j];
  __syncthreads();
  const float bn_scale = rsqrtf(1.0f + 1e-5f);
  for (int l = 0; l < 3; ++l){
    const float* W = fcW + (size_t)l*H*H;
    float acc = fcb[l*H + j];
    #pragma unroll 8
    for (int k = 0; k < H; ++k) acc += row[k] * W[k*H + j];
    acc = (acc > 0.f) ? acc : 0.01f*acc;             // leaky_relu
    acc = acc * bn_scale * gamma[l*H + j] + beta[l*H + j];
    __syncthreads();
    row[j] = acc;
    __syncthreads();
  }
  red[j] = row[j] * outW[j];
  __syncthreads();
  for (int o = 64; o > 0; o >>= 1){
    if (j < o) red[j] += red[j + o];
    __syncthreads();
  }
  if (j == 0) out[gi] = red[0] + outb[0];
}

extern "C" void kernel_launch(void* const* d_in, const int* in_sizes, int n_in,
                              void* d_out, int out_size, void* d_ws, size_t ws_size,
                              hipStream_t stream)
{
  const float* x    = (const float*)d_in[0];
  const int*   eii  = (const int*)  d_in[1];
  const int*   eie  = (const int*)  d_in[2];
  const float* pos  = (const float*)d_in[3];
  const float* ea   = (const float*)d_in[4];
  const int*   batch= (const int*)  d_in[5];
  const float* lnW  = (const float*)d_in[6];
  const float* lnb  = (const float*)d_in[7];
  const float* WIa  = (const float*)d_in[8];
  const float* bIa  = (const float*)d_in[9];
  const float* WEa  = (const float*)d_in[10];
  const float* bEa  = (const float*)d_in[11];
  const float* fcW  = (const float*)d_in[12];
  const float* fcb  = (const float*)d_in[13];
  const float* gam  = (const float*)d_in[14];
  const float* bet  = (const float*)d_in[15];
  const float* outW = (const float*)d_in[16];
  const float* outb = (const float*)d_in[17];
  float* out = (float*)d_out;

  const int* src_i = eii;  const int* dst_i = eii + EIN;
  const int* src_e = eie;  const int* dst_e = eie + EEX;

  const size_t NH = (size_t)NN * H;
  // layout: hA,hB,vp,vl (u16) | gp (f32) | cnt_i,cnt_e,row_i,row_e,cur_i,cur_e | col/val | bsum | Wf
  u16* hA = (u16*)d_ws;                    // NH
  u16* hB = hA + NH;
  u16* vp = hB + NH;
  u16* vl = vp + NH;
  float* gp = (float*)(vl + NH);           // NG*H
  int* cnt_i = (int*)(gp + (size_t)NG*H);  // NN
  int* cnt_e = cnt_i + NN;
  int* row_i = cnt_e + NN;
  int* row_e = row_i + NN;
  int* cur_i = row_e + NN;
  int* cur_e = cur_i + NN;
  int* col_i = cur_e + NN;                 // EIN
  float* val_i = (float*)(col_i + EIN);    // EIN
  int* col_e = (int*)(val_i + EIN);        // EEX
  float* val_e = (float*)(col_e + EEX);    // EEX
  int* bsum = (int*)(val_e + EEX);         // 1024
  u16* WfI = (u16*)(bsum + 1024);          // NL*H*H bf16
  u16* WfE = WfI + (size_t)NL*H*H;

  const size_t need = 4*NH*sizeof(u16)
                    + ((size_t)NG*H + 6*(size_t)NN + 2*(size_t)EIN + 2*(size_t)EEX + 1024)*4
                    + 2*(size_t)NL*H*H*sizeof(u16);
  if (ws_size < need) return;

  // ONE memset: vp, vl, gp, cnt_i, cnt_e are contiguous
  hipMemsetAsync(vp, 0, 2*NH*sizeof(u16) + (size_t)NG*H*sizeof(float) + 2*(size_t)NN*sizeof(int),
                 stream);

  k_prep<<<2*NL + NN/TML, 256, 0, stream>>>(x, lnW, lnb, hA, WIa, WEa, WfI, WfE);

  const int NE_ALL = EIN + EEX;
  k_count_all<<<(NE_ALL+255)/256, 256, 0, stream>>>(dst_i, dst_e, cnt_i, cnt_e);

  const int NB = (NN + 255)/256;  // 391
  k_block_sum_all<<<2*NB, 256, 0, stream>>>(cnt_i, cnt_e, bsum);
  k_scan_top_all<<<2, 512, 0, stream>>>(bsum);
  k_scan_write_all<<<2*NB, 256, 0, stream>>>(cnt_i, cnt_e, bsum, row_i, cur_i, row_e, cur_e);
  k_fill_all<<<(NE_ALL+255)/256, 256, 0, stream>>>(src_i, dst_i, ea, src_e, dst_e, pos,
                                                   cur_i, col_i, val_i, cur_e, col_e, val_e);

  const u16* hin = hA; u16* hout = hB;
  for (int l = 0; l < NL; ++l){
    k_layer<<<NTILES, 256, 0, stream>>>(hin, hout, vp, vl,
        row_i, cnt_i, col_i, val_i,
        row_e, cnt_e, col_e, val_e,
        WfI + (size_t)l*H*H, bIa + (size_t)l*H,
        WfE + (size_t)l*H*H, bEa + (size_t)l*H);
    u16* t = (u16*)hin; hin = hout; hout = t;
  }
  // after 4 swaps final h is back in hA == hin

  k_pool<<<(NN+63)/64, H, 0, stream>>>(hin, batch, gp);
  k_fc<<<NG, H, 0, stream>>>(gp, fcW, fcb, gam, bet, outW, outb, out);
}